// Round 3
// baseline (318.624 us; speedup 1.0000x reference)
//
#include <hip/hip_runtime.h>
#include <math.h>

#define BB 128   // batch
#define NN 96    // perturbations
#define DD 3072  // C*H*W
#define KK 10    // classes
#define G  4     // n's per block in k1

// ---------------- Kernel 1: logits + per-(n,b) losses ----------------
// grid = 3072 blocks = (B=128) * (96/G=24 n-groups), block = 256 threads.
// Thread t owns i = c*1024 + 4t .. +3 per chunk c (3 chunks), keeps the
// 4x10 W slice in registers, loops the 4 n's of its group. Reduction:
// one pairwise shfl_xor fold, then a 20 KB LDS transpose (8 blocks/CU).
__global__ __launch_bounds__(256) void k1_logits(
    const float* __restrict__ imgs,    // (128, 3072)
    const float* __restrict__ deltas,  // (96, 128, 3072)
    const float* __restrict__ W,       // (3072, 10)
    const float* __restrict__ bias,    // (10)
    const int*   __restrict__ labels,  // (128)
    float* __restrict__ l1_ws,         // (128, 96)
    float* __restrict__ l2_ws)         // (128, 96)
{
    const int t   = threadIdx.x;
    const int bid = blockIdx.x;
    const int b   = bid & 127;
    const int n0  = (bid >> 7) * G;

    float acc[G][KK];
#pragma unroll
    for (int j = 0; j < G; ++j)
#pragma unroll
        for (int k = 0; k < KK; ++k) acc[j][k] = 0.f;

#pragma unroll
    for (int c = 0; c < 3; ++c) {
        const int i0 = c * 1024 + t * 4;
        // Load W rows i0..i0+3 (40 consecutive floats, 16B-aligned)
        float w[40];
        const float4* wp = (const float4*)(W + (size_t)i0 * KK);
#pragma unroll
        for (int m = 0; m < 10; ++m) {
            float4 v = wp[m];
            w[4*m+0] = v.x; w[4*m+1] = v.y; w[4*m+2] = v.z; w[4*m+3] = v.w;
        }
        const float4 im = *(const float4*)(imgs + (size_t)b * DD + i0);
#pragma unroll
        for (int j = 0; j < G; ++j) {
            const int n = n0 + j;
            const float4 dl = *(const float4*)(deltas + ((size_t)(n * BB + b)) * DD + i0);
            const float x0 = fminf(fmaxf(im.x + dl.x, 0.f), 1.f);
            const float x1 = fminf(fmaxf(im.y + dl.y, 0.f), 1.f);
            const float x2 = fminf(fmaxf(im.z + dl.z, 0.f), 1.f);
            const float x3 = fminf(fmaxf(im.w + dl.w, 0.f), 1.f);
#pragma unroll
            for (int k = 0; k < KK; ++k) {
                acc[j][k] = fmaf(x3, w[30+k],
                            fmaf(x2, w[20+k],
                            fmaf(x1, w[10+k],
                            fmaf(x0, w[k], acc[j][k]))));
            }
        }
    }

    // Pairwise fold: after this, even lanes hold (lane + lane^1) sums.
    __shared__ float red[40 * 128];   // 20 KB
#pragma unroll
    for (int j = 0; j < G; ++j)
#pragma unroll
        for (int k = 0; k < KK; ++k) {
            float s = acc[j][k] + __shfl_xor(acc[j][k], 1, 64);
            acc[j][k] = s;
        }
    if ((t & 1) == 0) {
        const int col = t >> 1;   // 0..127
#pragma unroll
        for (int j = 0; j < G; ++j)
#pragma unroll
            for (int k = 0; k < KK; ++k)
                red[(j * KK + k) * 128 + col] = acc[j][k];
    }
    __syncthreads();

    const int wid  = t >> 6;   // wave id 0..3 -> handles n = n0 + wid
    const int lane = t & 63;
    float lg[KK];
#pragma unroll
    for (int k = 0; k < KK; ++k) {
        const float* row = red + (wid * KK + k) * 128;
        float s = row[lane] + row[lane + 64];
#pragma unroll
        for (int off = 32; off >= 1; off >>= 1)
            s += __shfl_down(s, off, 64);
        lg[k] = s;   // valid on lane 0
    }

    if (lane == 0) {
        const int n = n0 + wid;
#pragma unroll
        for (int k = 0; k < KK; ++k) lg[k] += bias[k];
        // top-1 (first max -> lower index on ties, matches lax.top_k)
        int top1 = 0; float m1 = lg[0];
#pragma unroll
        for (int k = 1; k < KK; ++k) if (lg[k] > m1) { m1 = lg[k]; top1 = k; }
        // second (first max among k != top1)
        int sec = (top1 == 0) ? 1 : 0; float m2 = lg[sec];
#pragma unroll
        for (int k = 0; k < KK; ++k)
            if (k != top1 && lg[k] > m2) { m2 = lg[k]; sec = k; }
        // log-sum-exp (max-stabilized, like jax log_softmax)
        float se = 0.f;
#pragma unroll
        for (int k = 0; k < KK; ++k) se += expf(lg[k] - m1);
        const float lse = m1 + logf(se);
        const int lab = labels[b];
        const float loss1 = lse - lg[lab];
        const float loss2 = (top1 == lab) ? (lse - lg[sec]) : -10000.0f;
        l1_ws[b * NN + n] = loss1;
        l2_ws[b * NN + n] = loss2;
    }
}

// ------- Kernel 2: stable rank-ind selection + final mean (1 block) -------
__global__ __launch_bounds__(1024) void k2_final(
    const float* __restrict__ l1_ws, const float* __restrict__ l2_ws,
    const int* __restrict__ ind_p, float* __restrict__ out)
{
    const int t = threadIdx.x;           // 0..1023
    __shared__ float sdiff[BB * NN];     // 48 KB
    __shared__ float sl2[BB * NN];       // 48 KB
    __shared__ float ssel[BB];
    __shared__ float wpart[16];

    float suml1 = 0.f;
#pragma unroll
    for (int r = 0; r < 12; ++r) {       // 12288 / 1024
        const int p = t + r * 1024;
        const float a = l1_ws[p];
        const float c = l2_ws[p];
        suml1 += a;
        sdiff[p] = a - c;
        sl2[p]   = c;
    }
    __syncthreads();

    const int ind = ind_p[0];
#pragma unroll
    for (int r = 0; r < 12; ++r) {
        const int p = t + r * 1024;
        const int b = p / NN;
        const int n = p - b * NN;
        const float d = sdiff[p];
        int rank = 0;
        const float* row = sdiff + b * NN;
        for (int j = 0; j < NN; ++j) {
            const float dj = row[j];
            rank += (dj < d) || (dj == d && j < n);   // stable argsort
        }
        if (rank == ind) ssel[b] = sl2[p];
    }

    // block sum of suml1
#pragma unroll
    for (int off = 32; off >= 1; off >>= 1) suml1 += __shfl_down(suml1, off, 64);
    if ((t & 63) == 0) wpart[t >> 6] = suml1;
    __syncthreads();
    if (t < 64) {
        float s  = (t < 16) ? wpart[t] : 0.f;
#pragma unroll
        for (int off = 8; off >= 1; off >>= 1) s += __shfl_down(s, off, 64);
        float se = ssel[t] + ssel[t + 64];
#pragma unroll
        for (int off = 32; off >= 1; off >>= 1) se += __shfl_down(se, off, 64);
        if (t == 0)
            out[0] = s / (96.0f * 128.0f) - se / 128.0f;
    }
}

extern "C" void kernel_launch(void* const* d_in, const int* in_sizes, int n_in,
                              void* d_out, int out_size, void* d_ws, size_t ws_size,
                              hipStream_t stream) {
    const float* imgs   = (const float*)d_in[0];
    const float* deltas = (const float*)d_in[1];
    const float* W      = (const float*)d_in[2];
    const float* bias   = (const float*)d_in[3];
    const int*   labels = (const int*)d_in[4];
    const int*   ind    = (const int*)d_in[5];
    float* out = (float*)d_out;

    float* l1_ws = (float*)d_ws;             // 12288 floats
    float* l2_ws = l1_ws + NN * BB;          // 12288 floats

    k1_logits<<<dim3(BB * (NN / G)), dim3(256), 0, stream>>>(
        imgs, deltas, W, bias, labels, l1_ws, l2_ws);
    k2_final<<<dim3(1), dim3(1024), 0, stream>>>(l1_ws, l2_ws, ind, out);
}

// Round 4
// 238.754 us; speedup vs baseline: 1.3345x; 1.3345x over previous
//
#include <hip/hip_runtime.h>
#include <hip/hip_bf16.h>
#include <math.h>

#define BB 128   // batch
#define NN 96    // perturbations
#define DD 3072  // C*H*W
#define KK 10    // classes
#define SPL 8    // K-splits = waves per block in k1
#define KST 12   // MFMA K-steps per wave: 3072 / (SPL*32)

typedef short s16x8 __attribute__((ext_vector_type(8)));
typedef float f32x4 __attribute__((ext_vector_type(4)));

// ---------------- Kernel 0: pack W into B-fragment layout ----------------
// Record r (0..6143): col=r&15, quad=(r>>4)&3, kb=r>>6. 16B record holds
// bf16 W[kb*32+quad*8+j][col], j=0..7 (zero for col>=10). Lane `l` of
// K-block kb then reads record kb*64+l with ONE coalesced dwordx4.
__global__ __launch_bounds__(256) void k0_pack(
    const float* __restrict__ W, unsigned short* __restrict__ pwg)
{
    const int r = blockIdx.x * 256 + threadIdx.x;   // 0..6143
    const int col  = r & 15;
    const int quad = (r >> 4) & 3;
    const int kb   = r >> 6;
    union { unsigned short us[8]; uint4 v; } rec;
#pragma unroll
    for (int j = 0; j < 8; ++j) {
        const int k = kb * 32 + quad * 8 + j;
        const float v = (col < KK) ? W[k * KK + col] : 0.0f;
        const __hip_bfloat16 h = __float2bfloat16(v);
        __builtin_memcpy(&rec.us[j], &h, 2);
    }
    ((uint4*)pwg)[r] = rec.v;
}

// ---------------- Kernel 1: MFMA logits + per-(n,b) losses ----------------
// grid = 768 blocks (one 16-row M-tile: rows r0..r0+15 = same n, b0..b0+15),
// block = 512 threads = 8 waves = 8 K-splits of 384. Each wave runs 12
// mfma_f32_16x16x32_bf16 steps; A built on the fly (clip(imgs+deltas)->bf16),
// B-frags are single coalesced 16B loads from pwg. LDS reduce + epilogue.
__global__ __launch_bounds__(512) void k1_mfma(
    const float* __restrict__ imgs,    // (128, 3072)
    const float* __restrict__ deltas,  // (96, 128, 3072)
    const unsigned short* __restrict__ pwg,
    const float* __restrict__ bias,    // (10)
    const int*   __restrict__ labels,  // (128)
    float* __restrict__ l1_ws,         // (128, 96)
    float* __restrict__ l2_ws)         // (128, 96)
{
    const int lane = threadIdx.x & 63;
    const int wv   = threadIdx.x >> 6;      // 0..7 = K-split
    const int tile = blockIdx.x;            // 0..767
    const int r0   = tile * 16;
    const int n    = r0 >> 7;               // constant over tile
    const int b0   = r0 & 127;
    const int m    = lane & 15;             // A row within tile
    const int quad = lane >> 4;

    const float* ap = deltas + (size_t)(r0 + m) * DD + wv * (KST * 32) + quad * 8;
    const float* ip = imgs   + (size_t)(b0 + m) * DD + wv * (KST * 32) + quad * 8;
    const unsigned short* wp = pwg + ((size_t)(wv * KST) * 64 + lane) * 8;

    f32x4 acc = {0.f, 0.f, 0.f, 0.f};
#pragma unroll 2
    for (int s = 0; s < KST; ++s) {
        const float4 d0 = *(const float4*)(ap);
        const float4 d1 = *(const float4*)(ap + 4);
        const float4 i0 = *(const float4*)(ip);
        const float4 i1 = *(const float4*)(ip + 4);
        const s16x8 bfrag = *(const s16x8*)(wp);
        float x[8];
        x[0] = d0.x + i0.x; x[1] = d0.y + i0.y; x[2] = d0.z + i0.z; x[3] = d0.w + i0.w;
        x[4] = d1.x + i1.x; x[5] = d1.y + i1.y; x[6] = d1.z + i1.z; x[7] = d1.w + i1.w;
        s16x8 afrag;
#pragma unroll
        for (int j = 0; j < 8; ++j) {
            const float xc = fminf(fmaxf(x[j], 0.f), 1.f);
            const __hip_bfloat16 h = __float2bfloat16(xc);
            unsigned short us; __builtin_memcpy(&us, &h, 2);
            afrag[j] = (short)us;
        }
        acc = __builtin_amdgcn_mfma_f32_16x16x32_bf16(afrag, bfrag, acc, 0, 0, 0);
        ap += 32; ip += 32; wp += 512;
    }

    // C layout (m89-verified): col = lane&15, row = quad*4 + reg.
    __shared__ float sred[SPL][16][16];     // 8 KB
#pragma unroll
    for (int reg = 0; reg < 4; ++reg)
        sred[wv][quad * 4 + reg][m] = acc[reg];
    __syncthreads();

    if (wv == 0 && lane < 16) {
        const int rr = lane;                // tile row -> b = b0+rr
        float lg[KK];
#pragma unroll
        for (int k = 0; k < KK; ++k) {
            float s = 0.f;
#pragma unroll
            for (int sp = 0; sp < SPL; ++sp) s += sred[sp][rr][k];
            lg[k] = s + bias[k];
        }
        // top-1 (first max -> lower index on ties, matches lax.top_k)
        int top1 = 0; float m1 = lg[0];
#pragma unroll
        for (int k = 1; k < KK; ++k) if (lg[k] > m1) { m1 = lg[k]; top1 = k; }
        int sec = (top1 == 0) ? 1 : 0; float m2 = lg[sec];
#pragma unroll
        for (int k = 0; k < KK; ++k)
            if (k != top1 && lg[k] > m2) { m2 = lg[k]; sec = k; }
        float se = 0.f;
#pragma unroll
        for (int k = 0; k < KK; ++k) se += expf(lg[k] - m1);
        const float lse = m1 + logf(se);
        const int b = b0 + rr;
        const int lab = labels[b];
        const float loss1 = lse - lg[lab];
        const float loss2 = (top1 == lab) ? (lse - lg[sec]) : -10000.0f;
        l1_ws[b * NN + n] = loss1;
        l2_ws[b * NN + n] = loss2;
    }
}

// ---------------- Kernel 2: per-b stable rank-ind selection ----------------
__global__ __launch_bounds__(128) void k2_select(
    const float* __restrict__ l1_ws, const float* __restrict__ l2_ws,
    const int* __restrict__ ind_p, float* __restrict__ perb)
{
    const int b = blockIdx.x;
    const int t = threadIdx.x;
    __shared__ float sd[NN];
    __shared__ float sl2[NN];
    __shared__ float ssel;
    __shared__ float swsum[2];

    float myl1 = 0.f, myd = 0.f;
    if (t < NN) {
        const float a = l1_ws[b * NN + t];
        const float c = l2_ws[b * NN + t];
        myl1 = a; myd = a - c;
        sd[t] = myd; sl2[t] = c;
    }
    __syncthreads();

    if (t < NN) {
        int rank = 0;
        for (int j = 0; j < NN; ++j) {
            const float dj = sd[j];
            rank += (dj < myd) || (dj == myd && j < t);  // stable argsort
        }
        if (rank == ind_p[0]) ssel = sl2[t];
    }

    float s = myl1;
#pragma unroll
    for (int off = 32; off >= 1; off >>= 1) s += __shfl_down(s, off, 64);
    if ((t & 63) == 0) swsum[t >> 6] = s;
    __syncthreads();
    if (t == 0) {
        const float total = swsum[0] + swsum[1];
        perb[b] = total / 96.0f - ssel;
    }
}

// ---------------- Kernel 3: final mean over b ----------------
__global__ __launch_bounds__(128) void k3_final(
    const float* __restrict__ perb, float* __restrict__ out)
{
    const int t = threadIdx.x;
    float s = perb[t];
#pragma unroll
    for (int off = 32; off >= 1; off >>= 1) s += __shfl_down(s, off, 64);
    __shared__ float sw[2];
    if ((t & 63) == 0) sw[t >> 6] = s;
    __syncthreads();
    if (t == 0) out[0] = (sw[0] + sw[1]) / 128.0f;
}

extern "C" void kernel_launch(void* const* d_in, const int* in_sizes, int n_in,
                              void* d_out, int out_size, void* d_ws, size_t ws_size,
                              hipStream_t stream) {
    const float* imgs   = (const float*)d_in[0];
    const float* deltas = (const float*)d_in[1];
    const float* W      = (const float*)d_in[2];
    const float* bias   = (const float*)d_in[3];
    const int*   labels = (const int*)d_in[4];
    const int*   ind    = (const int*)d_in[5];
    float* out = (float*)d_out;

    float* l1_ws = (float*)d_ws;                   // 12288 floats
    float* l2_ws = l1_ws + NN * BB;                // 12288 floats
    float* perb  = l2_ws + NN * BB;                // 128 floats
    unsigned short* pwg = (unsigned short*)(perb + BB);  // 96 KB packed W (16B-aligned)

    k0_pack<<<dim3(24), dim3(256), 0, stream>>>(W, pwg);
    k1_mfma<<<dim3(768), dim3(512), 0, stream>>>(
        imgs, deltas, pwg, bias, labels, l1_ws, l2_ws);
    k2_select<<<dim3(BB), dim3(128), 0, stream>>>(l1_ws, l2_ws, ind, perb);
    k3_final<<<dim3(1), dim3(128), 0, stream>>>(perb, out);
}